// Round 1
// baseline (316.297 us; speedup 1.0000x reference)
//
#include <hip/hip_runtime.h>

// LSTM B=4096, T=60, F=128, H=256. Round-8.
// Zero-sync, int8 weights, K=64 i8 MFMA. Changes vs R7 (156us lstm / 306 total):
//  - BRANCHLESS steady-state step: last timestep peeled out of the loop.
//    R7 had the gate math inside `if (t<T-1)` -> separate basic block -> the
//    scheduler could NOT overlap MFMA with gate VALU (MfmaUtil 26 + VALUBusy 53,
//    near-zero co-issue). Now one basic block per step.
//  - MFMA split by output half: phase A = acc[0..3] (hb0), phase B = acc[4..7]
//    (hb1) textually interleaved with hb0 gate cells (1 cell per ks round),
//    then hb1 cells. x-staging sits between phases to overlap MFMA issue.
//  - A-frags re-read per phase (6 extra ds_read_b128/wave-step) instead of held
//    live: keeps unified reg usage ~flat (<256 => 2 waves/SIMD preserved).

#define T_STEPS 60
#define F_DIM 128
#define H_DIM 256
#define BC 16
#define ZQ 31.75f
#define L2E 1.44269504f

typedef __attribute__((ext_vector_type(4))) int intx4;

__device__ __forceinline__ int q8(float v) {
    return __float2int_rn(fminf(fmaxf(v, -127.f), 127.f));
}

// Fused prep. Blocks 0..7: gate g=b>>1, column-half ch=b&1 (max+quant+pack).
// Block 8: head collapse (out = h.vhead + shead).
__global__ __launch_bounds__(1024)
void prep_kernel(const float* __restrict__ Wf, const float* __restrict__ Wu,
                 const float* __restrict__ Wc, const float* __restrict__ Wo,
                 const float* __restrict__ Wd1, const float* __restrict__ bd1,
                 const float* __restrict__ Wd2, const float* __restrict__ bd2,
                 float* __restrict__ cscale, intx4* __restrict__ qpack,
                 float* __restrict__ vhead, float* __restrict__ shead) {
    const int t = threadIdx.x;
    const int b = blockIdx.x;
    if (b < 8) {
        __shared__ float red[16][128];
        __shared__ float fsc[128];
        const int g = b >> 1, ch = b & 1;
        const float* W = (g == 0) ? Wf : (g == 1) ? Wu : (g == 2) ? Wc : Wo;
        const int col = ch * 128 + (t & 127);
        const int grp = t >> 7;                       // 0..7
        float mx = 1e-20f, mh = 1e-20f;
#pragma unroll 4
        for (int i = 0; i < 16; ++i)
            mx = fmaxf(mx, fabsf(W[(size_t)(grp * 16 + i) * H_DIM + col]));
#pragma unroll 4
        for (int i = 0; i < 32; ++i)
            mh = fmaxf(mh, fabsf(W[(size_t)(128 + grp * 32 + i) * H_DIM + col]));
        red[grp][t & 127] = mx;
        red[8 + grp][t & 127] = mh;
        __syncthreads();
        if (t < 128) {
            float Mx = red[0][t], Mh = red[8][t];
#pragma unroll
            for (int i = 1; i < 8; ++i) {
                Mx = fmaxf(Mx, red[i][t]);
                Mh = fmaxf(Mh, red[8 + i][t]);
            }
            float cs = fmaxf(4.f * Mx, Mh) * (1.f / 16129.f);
            cscale[g * 256 + ch * 128 + t] = cs;
            fsc[t] = 1.f / (127.f * cs);
        }
        __syncthreads();
        // pack: 8 hblk x 6 ks6 frags x 64 lanes = 3072 tasks
#pragma unroll
        for (int i = 0; i < 3; ++i) {
            int task = i * 1024 + t;
            int lane = task & 63, fr = task >> 6;     // fr 0..47
            int hl = fr / 6, ks6 = fr - hl * 6;
            int l15 = lane & 15, quad = lane >> 4;
            int colw = ch * 128 + hl * 16 + l15;
            int k0 = ks6 * 64 + quad * 16;
            float f = ((ks6 < 2) ? 4.f : 1.f) * fsc[hl * 16 + l15];
            int w[4];
#pragma unroll
            for (int d = 0; d < 4; ++d) {
                int b0 = q8(W[(size_t)(k0 + d * 4 + 0) * H_DIM + colw] * f) & 255;
                int b1 = q8(W[(size_t)(k0 + d * 4 + 1) * H_DIM + colw] * f) & 255;
                int b2 = q8(W[(size_t)(k0 + d * 4 + 2) * H_DIM + colw] * f) & 255;
                int b3 = q8(W[(size_t)(k0 + d * 4 + 3) * H_DIM + colw] * f) & 255;
                w[d] = b0 | (b1 << 8) | (b2 << 16) | (b3 << 24);
            }
            intx4 v = {w[0], w[1], w[2], w[3]};
            qpack[(((ch * 8 + hl) * 4 + g) * 6 + ks6) * 64 + lane] = v;
        }
    } else {
        __shared__ float hp[1024];
        const int j = t >> 2, q = t & 3;
        float s = 0.f;
        const float* row = Wd1 + (size_t)j * H_DIM + q * 64;
#pragma unroll
        for (int i = 0; i < 16; ++i) {
            float4 a = *(const float4*)(row + i * 4);
            float4 bb = *(const float4*)(Wd2 + q * 64 + i * 4);
            s += a.x * bb.x + a.y * bb.y + a.z * bb.z + a.w * bb.w;
        }
        hp[t] = s;
        __syncthreads();
        float vj = 0.f;
        if (q == 0) vj = hp[t] + hp[t + 1] + hp[t + 2] + hp[t + 3];
        __syncthreads();
        if (q == 0) vhead[j] = vj;
        if (t < 256) hp[t] = bd1[t] * Wd2[t];
        __syncthreads();
        for (int off = 128; off > 0; off >>= 1) {
            if (t < off) hp[t] += hp[t + off];
            __syncthreads();
        }
        if (t == 0) shead[0] = hp[0] + bd2[0];
    }
}

__global__ __launch_bounds__(512)
__attribute__((amdgpu_waves_per_eu(2, 2)))
void lstm_kernel(const float* __restrict__ x,
                 const float* __restrict__ bfv, const float* __restrict__ buv,
                 const float* __restrict__ bcv, const float* __restrict__ bov,
                 const intx4* __restrict__ qpack,
                 const float* __restrict__ cscale,
                 const float* __restrict__ vhead, const float* __restrict__ shead,
                 float* __restrict__ out)
{
    __shared__ __align__(16) intx4 wlds[64 * 64];              // ks6=5 slice, 64 KB
    __shared__ __align__(16) signed char zbuf[2][6][1024];     // double-buffered, 12 KB
    __shared__ float rowsum[BC];

    const int tid  = threadIdx.x;
    const int wave = tid >> 6;
    const int lane = tid & 63;
    const int quad = lane >> 4;
    const int l15  = lane & 15;
    const int b0   = blockIdx.x * BC;

    // ---- stage LDS weight slice (ks6 = 5) ----
    for (int i = tid; i < 64 * 64; i += 512)
        wlds[i] = qpack[((i >> 6) * 6 + 5) * 64 + (i & 63)];
    // ---- register weight slices (ks6 = 0..4), pinned ----
    intx4 wreg[5][8];
#pragma unroll
    for (int j = 0; j < 8; ++j)
#pragma unroll
        for (int ks = 0; ks < 5; ++ks) {
            intx4 v = qpack[(((8 * wave + j) * 6 + ks) * 64) + lane];
            int a0 = v[0], a1 = v[1], a2 = v[2], a3 = v[3];
            asm volatile("" : "+v"(a0), "+v"(a1), "+v"(a2), "+v"(a3));
            intx4 w = {a0, a1, a2, a3};
            wreg[ks][j] = w;
        }

    for (int i = tid; i < 2 * 6 * 1024 / 4; i += 512) ((int*)zbuf)[i] = 0;
    if (tid < BC) rowsum[tid] = 0.f;

    // ---- per-lane cell params (exp2 constants folded into dequant) ----
    float csS[2][4], bS[2][4], vh[2];
    float creg[2][4] = {};
    int haddr[2];
#pragma unroll
    for (int hb = 0; hb < 2; ++hb) {
        int a = 2 * wave + hb;
        int hc = a * 16 + l15;
        vh[hb] = vhead[hc];
        haddr[hb] = (2 + (a >> 2)) * 1024 + (a & 3) * 256 + l15;
#pragma unroll
        for (int g = 0; g < 4; ++g) {
            float cs = cscale[g * 256 + hc];
            float bi = (g == 0 ? bfv : g == 1 ? buv : g == 2 ? bcv : bov)[hc];
            float m = (g == 2) ? (-2.f * L2E) : (-L2E);
            csS[hb][g] = m * cs;
            bS[hb][g] = m * bi;
        }
    }

    // ---- x staging addresses ----
    const int xm = tid >> 5, xi = tid & 31;
    const int f0 = xi * 4;
    const int xaddr = (f0 >> 6) * 1024 + ((f0 & 63) >> 4) * 256 + xm * 16 + (f0 & 15);
    const float* xp = x + (size_t)(b0 + xm) * T_STEPS * F_DIM + f0;

    __syncthreads();
    float4 xv = *(const float4*)(xp);
    {
        unsigned u = (unsigned)(q8(xv.x * ZQ) & 255) | ((unsigned)(q8(xv.y * ZQ) & 255) << 8) |
                     ((unsigned)(q8(xv.z * ZQ) & 255) << 16) | ((unsigned)(q8(xv.w * ZQ) & 255) << 24);
        *(unsigned*)(&zbuf[0][0][0] + xaddr) = u;
    }
    xv = *(const float4*)(xp + F_DIM);
    __syncthreads();

    // One LSTM cell: dequant 4 gates -> activations (paired rcp) -> c,h update
    // -> quantize h byte into the other z-buffer.
#define GATE_CELL(hb, rr)                                                          \
    {                                                                              \
        float uf = fmaf((float)acc[(hb) * 4 + 0][rr], csS[hb][0], bS[hb][0]);      \
        float uu = fmaf((float)acc[(hb) * 4 + 1][rr], csS[hb][1], bS[hb][1]);      \
        float uc = fmaf((float)acc[(hb) * 4 + 2][rr], csS[hb][2], bS[hb][2]);      \
        float uo = fmaf((float)acc[(hb) * 4 + 3][rr], csS[hb][3], bS[hb][3]);      \
        float af = 1.f + __builtin_amdgcn_exp2f(uf);                               \
        float au = 1.f + __builtin_amdgcn_exp2f(uu);                               \
        float ac = 1.f + __builtin_amdgcn_exp2f(uc);                               \
        float ao = 1.f + __builtin_amdgcn_exp2f(uo);                               \
        float r1 = __builtin_amdgcn_rcpf(af * au);                                 \
        float r2 = __builtin_amdgcn_rcpf(ac * ao);                                 \
        float fg = au * r1;                                                        \
        float ug = af * r1;                                                        \
        float rc = ao * r2;                                                        \
        float og = ac * r2;                                                        \
        float cn = fmaf(fg, creg[hb][rr], fmaf(ug + ug, rc, -ug));                 \
        creg[hb][rr] = cn;                                                         \
        float rh = __builtin_amdgcn_rcpf(1.f + __builtin_amdgcn_exp2f(cn * (-2.f * L2E))); \
        float hn = fmaf(og + og, rh, -og);                                         \
        zw[haddr[hb] + (quad * 4 + (rr)) * 16] =                                   \
            (signed char)__float2int_rn(hn * 127.f);                               \
    }

#pragma unroll 1
    for (int t = 0; t < T_STEPS - 1; ++t) {
        const int p = t & 1;
        const intx4* zr = (const intx4*)(&zbuf[p][0][0]);
        signed char* zw = &zbuf[p ^ 1][0][0];

        intx4 acc[8] = {};

        // ---- phase A: hb0 outputs (j = 0..3), full K ----
#pragma unroll
        for (int ks = 0; ks < 6; ++ks) {
            intx4 a = zr[ks * 64 + lane];
            if (ks < 5) {
#pragma unroll
                for (int j = 0; j < 4; ++j)
                    acc[j] = __builtin_amdgcn_mfma_i32_16x16x64_i8(a, wreg[ks][j], acc[j], 0, 0, 0);
            } else {
#pragma unroll
                for (int j = 0; j < 4; ++j)
                    acc[j] = __builtin_amdgcn_mfma_i32_16x16x64_i8(
                        a, wlds[(8 * wave + j) * 64 + lane], acc[j], 0, 0, 0);
            }
        }

        // ---- stage x_{t+1}: independent of this step's compute, overlaps B ----
        {
            unsigned u = (unsigned)(q8(xv.x * ZQ) & 255) | ((unsigned)(q8(xv.y * ZQ) & 255) << 8) |
                         ((unsigned)(q8(xv.z * ZQ) & 255) << 16) | ((unsigned)(q8(xv.w * ZQ) & 255) << 24);
            *(unsigned*)(zw + xaddr) = u;
            int tn = (t + 2 < T_STEPS) ? (t + 2) : (T_STEPS - 1);   // clamp: last load is dummy
            xv = *(const float4*)(xp + (size_t)tn * F_DIM);
        }

        // ---- phase B: hb1 MFMAs (j = 4..7) interleaved with hb0 gate cells ----
#pragma unroll
        for (int ks = 0; ks < 6; ++ks) {
            intx4 a = zr[ks * 64 + lane];
            if (ks < 5) {
#pragma unroll
                for (int j = 4; j < 8; ++j)
                    acc[j] = __builtin_amdgcn_mfma_i32_16x16x64_i8(a, wreg[ks][j], acc[j], 0, 0, 0);
            } else {
#pragma unroll
                for (int j = 4; j < 8; ++j)
                    acc[j] = __builtin_amdgcn_mfma_i32_16x16x64_i8(
                        a, wlds[(8 * wave + j) * 64 + lane], acc[j], 0, 0, 0);
            }
            if (ks >= 1 && ks < 5) GATE_CELL(0, ks - 1);
        }
        // ---- hb1 gate cells ----
        GATE_CELL(1, 0);
        GATE_CELL(1, 1);
        GATE_CELL(1, 2);
        GATE_CELL(1, 3);

        __syncthreads();
    }

    // ---- peeled last step: MFMA + head collapse, no staging ----
    {
        const intx4* zr = (const intx4*)(&zbuf[(T_STEPS - 1) & 1][0][0]);
        intx4 acc[8] = {};
#pragma unroll
        for (int ks = 0; ks < 5; ++ks) {
            intx4 a = zr[ks * 64 + lane];
#pragma unroll
            for (int j = 0; j < 8; ++j)
                acc[j] = __builtin_amdgcn_mfma_i32_16x16x64_i8(a, wreg[ks][j], acc[j], 0, 0, 0);
        }
        {
            intx4 a5 = zr[5 * 64 + lane];
#pragma unroll
            for (int j = 0; j < 8; ++j) {
                intx4 bw = wlds[(8 * wave + j) * 64 + lane];
                acc[j] = __builtin_amdgcn_mfma_i32_16x16x64_i8(a5, bw, acc[j], 0, 0, 0);
            }
        }
        float hs[4] = {0.f, 0.f, 0.f, 0.f};
#pragma unroll
        for (int hb = 0; hb < 2; ++hb)
#pragma unroll
            for (int rr = 0; rr < 4; ++rr) {
                float uf = fmaf((float)acc[hb * 4 + 0][rr], csS[hb][0], bS[hb][0]);
                float uu = fmaf((float)acc[hb * 4 + 1][rr], csS[hb][1], bS[hb][1]);
                float uc = fmaf((float)acc[hb * 4 + 2][rr], csS[hb][2], bS[hb][2]);
                float uo = fmaf((float)acc[hb * 4 + 3][rr], csS[hb][3], bS[hb][3]);
                float af = 1.f + __builtin_amdgcn_exp2f(uf);
                float au = 1.f + __builtin_amdgcn_exp2f(uu);
                float ac = 1.f + __builtin_amdgcn_exp2f(uc);
                float ao = 1.f + __builtin_amdgcn_exp2f(uo);
                float r1 = __builtin_amdgcn_rcpf(af * au);
                float r2 = __builtin_amdgcn_rcpf(ac * ao);
                float fg = au * r1;
                float ug = af * r1;
                float rc = ao * r2;
                float og = ac * r2;
                float cn = fmaf(fg, creg[hb][rr], fmaf(ug + ug, rc, -ug));
                float rh = __builtin_amdgcn_rcpf(1.f + __builtin_amdgcn_exp2f(cn * (-2.f * L2E)));
                float hn = fmaf(og + og, rh, -og);
                hs[rr] += hn * vh[hb];
            }
#pragma unroll
        for (int rr = 0; rr < 4; ++rr) {
            float s = hs[rr];
#pragma unroll
            for (int m = 1; m < 16; m <<= 1)
                s += __shfl_xor(s, m, 64);
            if (l15 == 0)
                atomicAdd(&rowsum[quad * 4 + rr], s);
        }
        __syncthreads();
    }
#undef GATE_CELL

    if (tid < BC)
        out[b0 + tid] = rowsum[tid] + shead[0];
}

extern "C" void kernel_launch(void* const* d_in, const int* in_sizes, int n_in,
                              void* d_out, int out_size, void* d_ws, size_t ws_size,
                              hipStream_t stream) {
    (void)in_sizes; (void)n_in; (void)out_size; (void)ws_size;
    const float* x   = (const float*)d_in[0];
    const float* Wf  = (const float*)d_in[1];
    const float* bfv = (const float*)d_in[2];
    const float* Wu  = (const float*)d_in[3];
    const float* buv = (const float*)d_in[4];
    const float* Wc  = (const float*)d_in[5];
    const float* bcv = (const float*)d_in[6];
    const float* Wo  = (const float*)d_in[7];
    const float* bov = (const float*)d_in[8];
    const float* Wd1 = (const float*)d_in[9];
    const float* bd1 = (const float*)d_in[10];
    const float* Wd2 = (const float*)d_in[11];
    const float* bd2 = (const float*)d_in[12];

    char* ws = (char*)d_ws;
    intx4* qpack = (intx4*)ws;                               // 384 KB
    size_t off = (size_t)384 * 64 * 16;
    float* cscale = (float*)(ws + off); off += 1024 * 4;
    float* vhead  = (float*)(ws + off); off += 256 * 4;
    float* shead  = (float*)(ws + off); off += 16;

    prep_kernel<<<9, 1024, 0, stream>>>(Wf, Wu, Wc, Wo, Wd1, bd1, Wd2, bd2,
                                        cscale, qpack, vhead, shead);
    lstm_kernel<<<256, 512, 0, stream>>>(x, bfv, buv, bcv, bov, qpack, cscale,
                                         vhead, shead, (float*)d_out);
}